// Round 5
// baseline (783.493 us; speedup 1.0000x reference)
//
#include <hip/hip_runtime.h>
#include <hip/hip_bf16.h>
#include <stdint.h>

#define NWIN 4096

typedef __attribute__((ext_vector_type(8))) short bf16x8;
typedef __attribute__((ext_vector_type(4))) float f32x4;

// ws layout (bytes):
//   wq' bf16 [768][256] @0        (q/k rows permuted by pi within each 32-row head slice)
//   wp  bf16 [256][256] @393216
//   rb2 f32  [8][16][64][4] @524288   ([h][kt>>2][qt][kt&3], kt>=49 -> -1e30)
//   wsb f32  [768] @655360            (qkv bias, q/k permuted to match wq')
#define OFF_WQ 0LL
#define OFF_WP 393216LL
#define OFF_RB 524288LL
#define OFF_B  655360LL

static __device__ __forceinline__ uint32_t f2bf(float f) {
    union { float f; uint32_t u; } v; v.f = f;
    return (v.u + 0x7FFFu + ((v.u >> 16) & 1u)) >> 16;
}

static __device__ __forceinline__ uint32_t pk2(float lo, float hi) {
    union { __hip_bfloat162 h; uint32_t u; } c;
    c.h = __float22bfloat162_rn(float2{lo, hi});
    return c.u;
}

// pi: acc position p=16mt+4lg+i  ->  d = 8lg+4mt+i
static __device__ __forceinline__ int permd(int p) {
    return ((p >> 2) & 3) * 8 + (p >> 4) * 4 + (p & 3);
}

union FragU { uint32_t u[4]; bf16x8 v; };

// ---------------------------------------------------------------------------
// prep
// ---------------------------------------------------------------------------
__global__ void prep_kernel(const float* __restrict__ qkv_w, const float* __restrict__ proj_w,
                            const float* __restrict__ qkv_b,
                            const float* __restrict__ bias_table, const int* __restrict__ rel_index,
                            char* __restrict__ ws) {
    uint16_t* wq  = (uint16_t*)(ws + OFF_WQ);
    uint16_t* wp  = (uint16_t*)(ws + OFF_WP);
    float*    rb  = (float*)(ws + OFF_RB);
    float*    wsb = (float*)(ws + OFF_B);
    const int total = 196608 + 65536 + 32768 + 768;
    for (int idx = blockIdx.x * blockDim.x + threadIdx.x; idx < total;
         idx += gridDim.x * blockDim.x) {
        if (idx < 196608) {
            int n = idx >> 8, c = idx & 255;
            int src = (n < 512) ? ((n & ~31) | permd(n & 31)) : n;
            wq[idx] = (uint16_t)f2bf(qkv_w[src * 256 + c]);
        } else if (idx < 262144) {
            int i = idx - 196608;
            wp[i] = (uint16_t)f2bf(proj_w[i]);
        } else if (idx < 294912) {
            int i = idx - 262144;                 // [h][kt4][qt][ii]
            int h = i >> 12, kt4 = (i >> 8) & 15, qt = (i >> 2) & 63, ii = i & 3;
            int kt = kt4 * 4 + ii;
            float v = -1e30f;
            if (kt < 49 && qt < 49) v = bias_table[rel_index[qt * 49 + kt] * 8 + h];
            rb[i] = v;
        } else {
            int n = idx - 294912;
            int src = (n < 512) ? ((n & ~31) | permd(n & 31)) : n;
            wsb[n] = qkv_b[src];
        }
    }
}

// ---------------------------------------------------------------------------
// fused: 1 block = 1 window, 8 waves = 8 heads; LDS = X/O tile only.
// PV k-dim reordered by tau(32ks+8g+j)=16(2ks+(j>>2))+4g+(j&3) so BOTH the
// P->fragment and V->fragment conversions are pure in-lane packing (0 shuffles).
// ---------------------------------------------------------------------------
__global__ __launch_bounds__(512, 4) void fused_kernel(const float* __restrict__ x,
                                                       const float* __restrict__ proj_b,
                                                       float* __restrict__ out,
                                                       const char* __restrict__ ws) {
    __shared__ __align__(16) char smem[33792];   // X [64][264] bf16 ; later O [64][256] swz
    const int b = blockIdx.x;
    const int t = threadIdx.x, lane = t & 63, w = t >> 6;
    const int lr = lane & 15, lg = lane >> 4;
    const uint16_t* wq  = (const uint16_t*)(ws + OFF_WQ);
    const uint16_t* wp  = (const uint16_t*)(ws + OFF_WP);
    const float*    rb  = (const float*)(ws + OFF_RB);
    const float*    wsb = (const float*)(ws + OFF_B);
    uint16_t* X  = (uint16_t*)smem;
    char*     OL = smem;
    const float scale = 0.17677669529663687f;

    // ---- stage x -> LDS bf16 [64][264], rows>=49 zero ----
    {
        const float4* xv = (const float4*)x;
        #pragma unroll
        for (int it = 0; it < 8; ++it) {
            int idx = it * 512 + t;
            int row = idx >> 6, c4 = idx & 63;
            uint32_t lo = 0, hi = 0;
            if (row < 49) {
                float4 v4 = xv[((int64_t)b * 49 + row) * 64 + c4];
                lo = f2bf(v4.x) | (f2bf(v4.y) << 16);
                hi = f2bf(v4.z) | (f2bf(v4.w) << 16);
            }
            uint32_t* p = (uint32_t*)(X + row * 264 + c4 * 4);
            p[0] = lo; p[1] = hi;
        }
    }
    __syncthreads();

    // ---- phase A: q,k transposed GEMMs (A=W rows, B=X frags) -> qf, kf ----
    bf16x8 qf[4], kf[4];
    {
        f32x4 aq[2][4], ak[2][4];
        #pragma unroll
        for (int mt = 0; mt < 2; ++mt)
            #pragma unroll
            for (int t4 = 0; t4 < 4; ++t4) {
                aq[mt][t4] = (f32x4){0.f, 0.f, 0.f, 0.f};
                ak[mt][t4] = (f32x4){0.f, 0.f, 0.f, 0.f};
            }
        #pragma unroll
        for (int kk = 0; kk < 8; ++kk) {
            bf16x8 xf[4];
            #pragma unroll
            for (int t4 = 0; t4 < 4; ++t4)
                xf[t4] = *(const bf16x8*)(X + (16 * t4 + lr) * 264 + kk * 32 + lg * 8);
            #pragma unroll
            for (int mt = 0; mt < 2; ++mt) {
                bf16x8 wfq = *(const bf16x8*)(wq + (w * 32 + 16 * mt + lr) * 256 + kk * 32 + lg * 8);
                bf16x8 wfk = *(const bf16x8*)(wq + (256 + w * 32 + 16 * mt + lr) * 256 + kk * 32 + lg * 8);
                #pragma unroll
                for (int t4 = 0; t4 < 4; ++t4) {
                    aq[mt][t4] = __builtin_amdgcn_mfma_f32_16x16x32_bf16(wfq, xf[t4], aq[mt][t4], 0, 0, 0);
                    ak[mt][t4] = __builtin_amdgcn_mfma_f32_16x16x32_bf16(wfk, xf[t4], ak[mt][t4], 0, 0, 0);
                }
            }
        }
        f32x4 bq[2], bk[2];
        #pragma unroll
        for (int mt = 0; mt < 2; ++mt) {
            bq[mt] = *(const f32x4*)(wsb + w * 32 + 16 * mt + 4 * lg);
            bk[mt] = *(const f32x4*)(wsb + 256 + w * 32 + 16 * mt + 4 * lg);
        }
        #pragma unroll
        for (int t4 = 0; t4 < 4; ++t4) {
            FragU q, k;
            #pragma unroll
            for (int mt = 0; mt < 2; ++mt) {
                q.u[2 * mt]     = pk2(aq[mt][t4][0] + bq[mt][0], aq[mt][t4][1] + bq[mt][1]);
                q.u[2 * mt + 1] = pk2(aq[mt][t4][2] + bq[mt][2], aq[mt][t4][3] + bq[mt][3]);
                k.u[2 * mt]     = pk2(ak[mt][t4][0] + bk[mt][0], ak[mt][t4][1] + bk[mt][1]);
                k.u[2 * mt + 1] = pk2(ak[mt][t4][2] + bk[mt][2], ak[mt][t4][3] + bk[mt][3]);
            }
            qf[t4] = q.v; kf[t4] = k.v;
        }
    }

    // ---- phase B: v GEMM (A=X frags, B=Wv rows) + in-lane pack to vf ----
    bf16x8 vf[2][2];   // [dt][ks]
    {
        f32x4 av[4][2];
        #pragma unroll
        for (int t4 = 0; t4 < 4; ++t4)
            #pragma unroll
            for (int dn = 0; dn < 2; ++dn)
                av[t4][dn] = (f32x4){0.f, 0.f, 0.f, 0.f};
        #pragma unroll
        for (int kk = 0; kk < 8; ++kk) {
            bf16x8 xf[4];
            #pragma unroll
            for (int t4 = 0; t4 < 4; ++t4)
                xf[t4] = *(const bf16x8*)(X + (16 * t4 + lr) * 264 + kk * 32 + lg * 8);
            #pragma unroll
            for (int dn = 0; dn < 2; ++dn) {
                bf16x8 wf = *(const bf16x8*)(wq + (512 + w * 32 + 16 * dn + lr) * 256 + kk * 32 + lg * 8);
                #pragma unroll
                for (int t4 = 0; t4 < 4; ++t4)
                    av[t4][dn] = __builtin_amdgcn_mfma_f32_16x16x32_bf16(xf[t4], wf, av[t4][dn], 0, 0, 0);
            }
        }
        #pragma unroll
        for (int dt = 0; dt < 2; ++dt) {
            const float bv = wsb[512 + w * 32 + 16 * dt + lr];
            #pragma unroll
            for (int ks = 0; ks < 2; ++ks) {
                FragU f;
                f.u[0] = pk2(av[2 * ks][dt][0] + bv, av[2 * ks][dt][1] + bv);
                f.u[1] = pk2(av[2 * ks][dt][2] + bv, av[2 * ks][dt][3] + bv);
                f.u[2] = pk2(av[2 * ks + 1][dt][0] + bv, av[2 * ks + 1][dt][1] + bv);
                f.u[3] = pk2(av[2 * ks + 1][dt][2] + bv, av[2 * ks + 1][dt][3] + bv);
                vf[dt][ks] = f.v;
            }
        }
    }

    // ---- phase C/D/E streamed per qt-group: S col, softmax, pack, PV ----
    float rs[4];
    f32x4 o[2][4];
    #pragma unroll
    for (int nj = 0; nj < 4; ++nj) {
        f32x4 s[4];
        #pragma unroll
        for (int mj = 0; mj < 4; ++mj)
            s[mj] = __builtin_amdgcn_mfma_f32_16x16x32_bf16(
                kf[mj], qf[nj], (f32x4){0.f, 0.f, 0.f, 0.f}, 0, 0, 0);
        #pragma unroll
        for (int mj = 0; mj < 4; ++mj) {
            f32x4 rbv = *(const f32x4*)(rb + ((w * 16 + 4 * mj + lg) * 64 + 16 * nj + lr) * 4);
            s[mj] = s[mj] * scale + rbv;
        }
        float m = s[0][0];
        #pragma unroll
        for (int mj = 0; mj < 4; ++mj)
            #pragma unroll
            for (int i = 0; i < 4; ++i) m = fmaxf(m, s[mj][i]);
        m = fmaxf(m, __shfl_xor(m, 16));
        m = fmaxf(m, __shfl_xor(m, 32));
        float sum = 0.f;
        #pragma unroll
        for (int mj = 0; mj < 4; ++mj)
            #pragma unroll
            for (int i = 0; i < 4; ++i) {
                float e = __expf(s[mj][i] - m);
                s[mj][i] = e;
                sum += e;
            }
        sum += __shfl_xor(sum, 16);
        sum += __shfl_xor(sum, 32);
        rs[nj] = sum;
        // in-lane pack: fragment ks = pack(s[2ks], s[2ks+1])  (tau ordering)
        #pragma unroll
        for (int ks = 0; ks < 2; ++ks) {
            FragU f;
            f.u[0] = pk2(s[2 * ks][0], s[2 * ks][1]);
            f.u[1] = pk2(s[2 * ks][2], s[2 * ks][3]);
            f.u[2] = pk2(s[2 * ks + 1][0], s[2 * ks + 1][1]);
            f.u[3] = pk2(s[2 * ks + 1][2], s[2 * ks + 1][3]);
            #pragma unroll
            for (int dt = 0; dt < 2; ++dt) {
                f32x4 c = (ks == 0) ? (f32x4){0.f, 0.f, 0.f, 0.f} : o[dt][nj];
                o[dt][nj] = __builtin_amdgcn_mfma_f32_16x16x32_bf16(vf[dt][ks], f.v, c, 0, 0, 0);
            }
        }
    }

    // ---- phase F: normalize, O -> LDS (overlay X) ----
    __syncthreads();
    #pragma unroll
    for (int nj = 0; nj < 4; ++nj) {
        const float rinv = 1.0f / rs[nj];
        const int row = 16 * nj + lr;
        const int swz = (row & 7) << 4;
        #pragma unroll
        for (int dt = 0; dt < 2; ++dt) {
            uint2 pk;
            pk.x = pk2(o[dt][nj][0] * rinv, o[dt][nj][1] * rinv);
            pk.y = pk2(o[dt][nj][2] * rinv, o[dt][nj][3] * rinv);
            *(uint2*)(OL + ((row * 512 + w * 64 + dt * 32 + lg * 8) ^ swz)) = pk;
        }
    }
    __syncthreads();

    // ---- phase G: proj GEMM [64x256]@[256x256]^T + bias -> out ----
    const int wm = w >> 2, wn = w & 3;
    f32x4 pacc[2][4];
    #pragma unroll
    for (int mi = 0; mi < 2; ++mi)
        #pragma unroll
        for (int nj = 0; nj < 4; ++nj)
            pacc[mi][nj] = (f32x4){0.f, 0.f, 0.f, 0.f};
    #pragma unroll
    for (int kk = 0; kk < 8; ++kk) {
        bf16x8 av[2];
        #pragma unroll
        for (int mi = 0; mi < 2; ++mi) {
            const int row = wm * 32 + mi * 16 + lr;
            av[mi] = *(const bf16x8*)(OL + ((row * 512 + kk * 64 + lg * 16) ^ ((row & 7) << 4)));
        }
        #pragma unroll
        for (int nj = 0; nj < 4; ++nj) {
            bf16x8 bv = *(const bf16x8*)(wp + (wn * 64 + nj * 16 + lr) * 256 + kk * 32 + lg * 8);
            #pragma unroll
            for (int mi = 0; mi < 2; ++mi)
                pacc[mi][nj] = __builtin_amdgcn_mfma_f32_16x16x32_bf16(av[mi], bv, pacc[mi][nj], 0, 0, 0);
        }
    }
    #pragma unroll
    for (int nj = 0; nj < 4; ++nj) {
        const int n = wn * 64 + nj * 16 + lr;
        const float pb = proj_b[n];
        #pragma unroll
        for (int mi = 0; mi < 2; ++mi)
            #pragma unroll
            for (int i = 0; i < 4; ++i) {
                const int tok = wm * 32 + mi * 16 + lg * 4 + i;
                if (tok < 49)
                    out[((int64_t)b * 49 + tok) * 256 + n] = pacc[mi][nj][i] + pb;
            }
    }
}

extern "C" void kernel_launch(void* const* d_in, const int* in_sizes, int n_in,
                              void* d_out, int out_size, void* d_ws, size_t ws_size,
                              hipStream_t stream) {
    const float* x          = (const float*)d_in[0];
    const float* qkv_w      = (const float*)d_in[1];
    const float* qkv_b      = (const float*)d_in[2];
    const float* proj_w     = (const float*)d_in[3];
    const float* proj_b     = (const float*)d_in[4];
    const float* bias_table = (const float*)d_in[5];
    const int*   rel_index  = (const int*)d_in[6];
    float* out = (float*)d_out;
    char*  ws  = (char*)d_ws;

    prep_kernel<<<1155, 256, 0, stream>>>(qkv_w, proj_w, qkv_b, bias_table, rel_index, ws);
    fused_kernel<<<NWIN, 512, 0, stream>>>(x, proj_b, out, ws);
}

// Round 6
// 412.170 us; speedup vs baseline: 1.9009x; 1.9009x over previous
//
#include <hip/hip_runtime.h>
#include <hip/hip_bf16.h>
#include <stdint.h>

#define NWIN 4096

typedef __attribute__((ext_vector_type(8))) short bf16x8;
typedef __attribute__((ext_vector_type(4))) float f32x4;

// ws layout (bytes):
//   wq' bf16 [768][256] @0        (q/k rows permuted by pi within each 32-row head slice)
//   wp  bf16 [256][256] @393216
//   rb2 f32  [8][16][64][4] @524288   ([h][kt>>2][qt][kt&3], kt>=49 -> -1e30)
//   wsb f32  [768] @655360            (qkv bias, q/k permuted to match wq')
#define OFF_WQ 0LL
#define OFF_WP 393216LL
#define OFF_RB 524288LL
#define OFF_B  655360LL

static __device__ __forceinline__ uint32_t f2bf(float f) {
    union { float f; uint32_t u; } v; v.f = f;
    return (v.u + 0x7FFFu + ((v.u >> 16) & 1u)) >> 16;
}

static __device__ __forceinline__ uint32_t pk2(float lo, float hi) {
    union { __hip_bfloat162 h; uint32_t u; } c;
    c.h = __float22bfloat162_rn(float2{lo, hi});
    return c.u;
}

// pi: acc position p=16mt+4lg+i  ->  d = 8lg+4mt+i
static __device__ __forceinline__ int permd(int p) {
    return ((p >> 2) & 3) * 8 + (p >> 4) * 4 + (p & 3);
}

union FragU { uint32_t u[4]; bf16x8 v; };

// ---------------------------------------------------------------------------
// prep
// ---------------------------------------------------------------------------
__global__ void prep_kernel(const float* __restrict__ qkv_w, const float* __restrict__ proj_w,
                            const float* __restrict__ qkv_b,
                            const float* __restrict__ bias_table, const int* __restrict__ rel_index,
                            char* __restrict__ ws) {
    uint16_t* wq  = (uint16_t*)(ws + OFF_WQ);
    uint16_t* wp  = (uint16_t*)(ws + OFF_WP);
    float*    rb  = (float*)(ws + OFF_RB);
    float*    wsb = (float*)(ws + OFF_B);
    const int total = 196608 + 65536 + 32768 + 768;
    for (int idx = blockIdx.x * blockDim.x + threadIdx.x; idx < total;
         idx += gridDim.x * blockDim.x) {
        if (idx < 196608) {
            int n = idx >> 8, c = idx & 255;
            int src = (n < 512) ? ((n & ~31) | permd(n & 31)) : n;
            wq[idx] = (uint16_t)f2bf(qkv_w[src * 256 + c]);
        } else if (idx < 262144) {
            int i = idx - 196608;
            wp[i] = (uint16_t)f2bf(proj_w[i]);
        } else if (idx < 294912) {
            int i = idx - 262144;                 // [h][kt4][qt][ii]
            int h = i >> 12, kt4 = (i >> 8) & 15, qt = (i >> 2) & 63, ii = i & 3;
            int kt = kt4 * 4 + ii;
            float v = -1e30f;
            if (kt < 49 && qt < 49) v = bias_table[rel_index[qt * 49 + kt] * 8 + h];
            rb[i] = v;
        } else {
            int n = idx - 294912;
            int src = (n < 512) ? ((n & ~31) | permd(n & 31)) : n;
            wsb[n] = qkv_b[src];
        }
    }
}

// ---------------------------------------------------------------------------
// fused: 1 block = 1 window, 8 waves = 8 heads; LDS = X/O tile only.
// Round-4 phase schedule (proven no-spill) + tau in-lane fragment packing
// (round-5 algebra, proven correct): tau(32ks+8g+j)=16(2ks+(j>>2))+4g+(j&3)
// applied to BOTH P and V k-slots -> zero cross-lane shuffles in packing.
// ---------------------------------------------------------------------------
__global__ __launch_bounds__(512, 4) void fused_kernel(const float* __restrict__ x,
                                                       const float* __restrict__ proj_b,
                                                       float* __restrict__ out,
                                                       const char* __restrict__ ws) {
    __shared__ __align__(16) char smem[33792];   // X [64][264] bf16 ; later O [64][256] swz
    const int b = blockIdx.x;
    const int t = threadIdx.x, lane = t & 63, w = t >> 6;
    const int lr = lane & 15, lg = lane >> 4;
    const uint16_t* wq  = (const uint16_t*)(ws + OFF_WQ);
    const uint16_t* wp  = (const uint16_t*)(ws + OFF_WP);
    const float*    rb  = (const float*)(ws + OFF_RB);
    const float*    wsb = (const float*)(ws + OFF_B);
    uint16_t* X  = (uint16_t*)smem;
    char*     OL = smem;
    const float scale = 0.17677669529663687f;

    // ---- stage x -> LDS bf16 [64][264], rows>=49 zero ----
    {
        const float4* xv = (const float4*)x;
        #pragma unroll
        for (int it = 0; it < 8; ++it) {
            int idx = it * 512 + t;
            int row = idx >> 6, c4 = idx & 63;
            uint32_t lo = 0, hi = 0;
            if (row < 49) {
                float4 v4 = xv[((int64_t)b * 49 + row) * 64 + c4];
                lo = f2bf(v4.x) | (f2bf(v4.y) << 16);
                hi = f2bf(v4.z) | (f2bf(v4.w) << 16);
            }
            uint32_t* p = (uint32_t*)(X + row * 264 + c4 * 4);
            p[0] = lo; p[1] = hi;
        }
    }
    __syncthreads();

    // ---- phase A: q,k transposed GEMMs (A=W rows, B=X frags) -> qf, kf ----
    bf16x8 qf[4], kf[4];
    {
        f32x4 aq[2][4], ak[2][4];
        #pragma unroll
        for (int mt = 0; mt < 2; ++mt)
            #pragma unroll
            for (int t4 = 0; t4 < 4; ++t4) {
                aq[mt][t4] = (f32x4){0.f, 0.f, 0.f, 0.f};
                ak[mt][t4] = (f32x4){0.f, 0.f, 0.f, 0.f};
            }
        #pragma unroll
        for (int kk = 0; kk < 8; ++kk) {
            bf16x8 xf[4];
            #pragma unroll
            for (int t4 = 0; t4 < 4; ++t4)
                xf[t4] = *(const bf16x8*)(X + (16 * t4 + lr) * 264 + kk * 32 + lg * 8);
            #pragma unroll
            for (int mt = 0; mt < 2; ++mt) {
                bf16x8 wfq = *(const bf16x8*)(wq + (w * 32 + 16 * mt + lr) * 256 + kk * 32 + lg * 8);
                bf16x8 wfk = *(const bf16x8*)(wq + (256 + w * 32 + 16 * mt + lr) * 256 + kk * 32 + lg * 8);
                #pragma unroll
                for (int t4 = 0; t4 < 4; ++t4) {
                    aq[mt][t4] = __builtin_amdgcn_mfma_f32_16x16x32_bf16(wfq, xf[t4], aq[mt][t4], 0, 0, 0);
                    ak[mt][t4] = __builtin_amdgcn_mfma_f32_16x16x32_bf16(wfk, xf[t4], ak[mt][t4], 0, 0, 0);
                }
            }
        }
        f32x4 bq[2], bk[2];
        #pragma unroll
        for (int mt = 0; mt < 2; ++mt) {
            bq[mt] = *(const f32x4*)(wsb + w * 32 + 16 * mt + 4 * lg);
            bk[mt] = *(const f32x4*)(wsb + 256 + w * 32 + 16 * mt + 4 * lg);
        }
        #pragma unroll
        for (int t4 = 0; t4 < 4; ++t4) {
            FragU q, k;
            #pragma unroll
            for (int mt = 0; mt < 2; ++mt) {
                q.u[2 * mt]     = pk2(aq[mt][t4][0] + bq[mt][0], aq[mt][t4][1] + bq[mt][1]);
                q.u[2 * mt + 1] = pk2(aq[mt][t4][2] + bq[mt][2], aq[mt][t4][3] + bq[mt][3]);
                k.u[2 * mt]     = pk2(ak[mt][t4][0] + bk[mt][0], ak[mt][t4][1] + bk[mt][1]);
                k.u[2 * mt + 1] = pk2(ak[mt][t4][2] + bk[mt][2], ak[mt][t4][3] + bk[mt][3]);
            }
            qf[t4] = q.v; kf[t4] = k.v;
        }
    }

    // ---- phase C/D streamed per qt-group: S col, softmax, tau-pack pf ----
    float rs[4];
    bf16x8 pf[4][2];
    #pragma unroll
    for (int nj = 0; nj < 4; ++nj) {
        f32x4 s[4];
        #pragma unroll
        for (int mj = 0; mj < 4; ++mj)
            s[mj] = __builtin_amdgcn_mfma_f32_16x16x32_bf16(
                kf[mj], qf[nj], (f32x4){0.f, 0.f, 0.f, 0.f}, 0, 0, 0);
        #pragma unroll
        for (int mj = 0; mj < 4; ++mj) {
            f32x4 rbv = *(const f32x4*)(rb + ((w * 16 + 4 * mj + lg) * 64 + 16 * nj + lr) * 4);
            s[mj] = s[mj] * scale + rbv;
        }
        float m = s[0][0];
        #pragma unroll
        for (int mj = 0; mj < 4; ++mj)
            #pragma unroll
            for (int i = 0; i < 4; ++i) m = fmaxf(m, s[mj][i]);
        m = fmaxf(m, __shfl_xor(m, 16));
        m = fmaxf(m, __shfl_xor(m, 32));
        float sum = 0.f;
        #pragma unroll
        for (int mj = 0; mj < 4; ++mj)
            #pragma unroll
            for (int i = 0; i < 4; ++i) {
                float e = __expf(s[mj][i] - m);
                s[mj][i] = e;
                sum += e;
            }
        sum += __shfl_xor(sum, 16);
        sum += __shfl_xor(sum, 32);
        rs[nj] = sum;
        // in-lane tau pack: fragment ks = pack(s[2ks], s[2ks+1])
        #pragma unroll
        for (int ks = 0; ks < 2; ++ks) {
            FragU f;
            f.u[0] = pk2(s[2 * ks][0], s[2 * ks][1]);
            f.u[1] = pk2(s[2 * ks][2], s[2 * ks][3]);
            f.u[2] = pk2(s[2 * ks + 1][0], s[2 * ks + 1][1]);
            f.u[3] = pk2(s[2 * ks + 1][2], s[2 * ks + 1][3]);
            pf[nj][ks] = f.v;
        }
    }

    // keep v-GEMM loads/MFMAs from being hoisted into the softmax region
    __builtin_amdgcn_sched_barrier(0);

    // ---- phase B: v GEMM (A=X frags, B=Wv rows) + in-lane tau pack vf ----
    bf16x8 vf[2][2];   // [dt][ks]
    {
        f32x4 av[4][2];
        #pragma unroll
        for (int t4 = 0; t4 < 4; ++t4)
            #pragma unroll
            for (int dn = 0; dn < 2; ++dn)
                av[t4][dn] = (f32x4){0.f, 0.f, 0.f, 0.f};
        #pragma unroll
        for (int kk = 0; kk < 8; ++kk) {
            bf16x8 xf[4];
            #pragma unroll
            for (int t4 = 0; t4 < 4; ++t4)
                xf[t4] = *(const bf16x8*)(X + (16 * t4 + lr) * 264 + kk * 32 + lg * 8);
            #pragma unroll
            for (int dn = 0; dn < 2; ++dn) {
                bf16x8 wf = *(const bf16x8*)(wq + (512 + w * 32 + 16 * dn + lr) * 256 + kk * 32 + lg * 8);
                #pragma unroll
                for (int t4 = 0; t4 < 4; ++t4)
                    av[t4][dn] = __builtin_amdgcn_mfma_f32_16x16x32_bf16(xf[t4], wf, av[t4][dn], 0, 0, 0);
            }
        }
        #pragma unroll
        for (int dt = 0; dt < 2; ++dt) {
            const float bv = wsb[512 + w * 32 + 16 * dt + lr];
            #pragma unroll
            for (int ks = 0; ks < 2; ++ks) {
                FragU f;
                f.u[0] = pk2(av[2 * ks][dt][0] + bv, av[2 * ks][dt][1] + bv);
                f.u[1] = pk2(av[2 * ks][dt][2] + bv, av[2 * ks][dt][3] + bv);
                f.u[2] = pk2(av[2 * ks + 1][dt][0] + bv, av[2 * ks + 1][dt][1] + bv);
                f.u[3] = pk2(av[2 * ks + 1][dt][2] + bv, av[2 * ks + 1][dt][3] + bv);
                vf[dt][ks] = f.v;
            }
        }
    }

    // ---- phase E: O^T = V^T · P^T (tau-consistent k-slots) ----
    f32x4 o[2][4];
    #pragma unroll
    for (int dt = 0; dt < 2; ++dt)
        #pragma unroll
        for (int nj = 0; nj < 4; ++nj) {
            f32x4 acc = __builtin_amdgcn_mfma_f32_16x16x32_bf16(
                vf[dt][0], pf[nj][0], (f32x4){0.f, 0.f, 0.f, 0.f}, 0, 0, 0);
            o[dt][nj] = __builtin_amdgcn_mfma_f32_16x16x32_bf16(vf[dt][1], pf[nj][1], acc, 0, 0, 0);
        }

    // ---- phase F: normalize, O -> LDS (overlay X) ----
    __syncthreads();
    #pragma unroll
    for (int nj = 0; nj < 4; ++nj) {
        const float rinv = 1.0f / rs[nj];
        const int row = 16 * nj + lr;
        const int swz = (row & 7) << 4;
        #pragma unroll
        for (int dt = 0; dt < 2; ++dt) {
            uint2 pk;
            pk.x = pk2(o[dt][nj][0] * rinv, o[dt][nj][1] * rinv);
            pk.y = pk2(o[dt][nj][2] * rinv, o[dt][nj][3] * rinv);
            *(uint2*)(OL + ((row * 512 + w * 64 + dt * 32 + lg * 8) ^ swz)) = pk;
        }
    }
    __syncthreads();

    // ---- phase G: proj GEMM [64x256]@[256x256]^T + bias -> out ----
    const int wm = w >> 2, wn = w & 3;
    f32x4 pacc[2][4];
    #pragma unroll
    for (int mi = 0; mi < 2; ++mi)
        #pragma unroll
        for (int nj = 0; nj < 4; ++nj)
            pacc[mi][nj] = (f32x4){0.f, 0.f, 0.f, 0.f};
    #pragma unroll
    for (int kk = 0; kk < 8; ++kk) {
        bf16x8 av[2];
        #pragma unroll
        for (int mi = 0; mi < 2; ++mi) {
            const int row = wm * 32 + mi * 16 + lr;
            av[mi] = *(const bf16x8*)(OL + ((row * 512 + kk * 64 + lg * 16) ^ ((row & 7) << 4)));
        }
        #pragma unroll
        for (int nj = 0; nj < 4; ++nj) {
            bf16x8 bv = *(const bf16x8*)(wp + (wn * 64 + nj * 16 + lr) * 256 + kk * 32 + lg * 8);
            #pragma unroll
            for (int mi = 0; mi < 2; ++mi)
                pacc[mi][nj] = __builtin_amdgcn_mfma_f32_16x16x32_bf16(av[mi], bv, pacc[mi][nj], 0, 0, 0);
        }
    }
    #pragma unroll
    for (int nj = 0; nj < 4; ++nj) {
        const int n = wn * 64 + nj * 16 + lr;
        const float pb = proj_b[n];
        #pragma unroll
        for (int mi = 0; mi < 2; ++mi)
            #pragma unroll
            for (int i = 0; i < 4; ++i) {
                const int tok = wm * 32 + mi * 16 + lg * 4 + i;
                if (tok < 49)
                    out[((int64_t)b * 49 + tok) * 256 + n] = pacc[mi][nj][i] + pb;
            }
    }
}

extern "C" void kernel_launch(void* const* d_in, const int* in_sizes, int n_in,
                              void* d_out, int out_size, void* d_ws, size_t ws_size,
                              hipStream_t stream) {
    const float* x          = (const float*)d_in[0];
    const float* qkv_w      = (const float*)d_in[1];
    const float* qkv_b      = (const float*)d_in[2];
    const float* proj_w     = (const float*)d_in[3];
    const float* proj_b     = (const float*)d_in[4];
    const float* bias_table = (const float*)d_in[5];
    const int*   rel_index  = (const int*)d_in[6];
    float* out = (float*)d_out;
    char*  ws  = (char*)d_ws;

    prep_kernel<<<1155, 256, 0, stream>>>(qkv_w, proj_w, qkv_b, bias_table, rel_index, ws);
    fused_kernel<<<NWIN, 512, 0, stream>>>(x, proj_b, out, ws);
}

// Round 7
// 394.346 us; speedup vs baseline: 1.9868x; 1.0452x over previous
//
#include <hip/hip_runtime.h>
#include <hip/hip_bf16.h>
#include <stdint.h>

#define NWIN 4096

typedef __attribute__((ext_vector_type(8))) short bf16x8;
typedef __attribute__((ext_vector_type(4))) float f32x4;

// ws layout (bytes):
//   wq' bf16 [768][256] @0        (q/k rows permuted by pi within each 32-row head slice)
//   wp  bf16 [256][256] @393216
//   rb2 f32  [8][16][64][4] @524288   ([h][kt>>2][qt][kt&3], *1/ln2, kt>=49 -> -1e30)
//   wsb f32  [768] @655360            (qkv bias, q/k permuted to match wq')
#define OFF_WQ 0LL
#define OFF_WP 393216LL
#define OFF_RB 524288LL
#define OFF_B  655360LL

static __device__ __forceinline__ uint32_t f2bf(float f) {
    union { float f; uint32_t u; } v; v.f = f;
    return (v.u + 0x7FFFu + ((v.u >> 16) & 1u)) >> 16;
}

static __device__ __forceinline__ uint32_t pk2(float lo, float hi) {
    union { __hip_bfloat162 h; uint32_t u; } c;
    c.h = __float22bfloat162_rn(float2{lo, hi});
    return c.u;
}

// pi: acc position p=16mt+4lg+i  ->  d = 8lg+4mt+i
static __device__ __forceinline__ int permd(int p) {
    return ((p >> 2) & 3) * 8 + (p >> 4) * 4 + (p & 3);
}

union FragU { uint32_t u[4]; bf16x8 v; };

// ---------------------------------------------------------------------------
// prep
// ---------------------------------------------------------------------------
__global__ void prep_kernel(const float* __restrict__ qkv_w, const float* __restrict__ proj_w,
                            const float* __restrict__ qkv_b,
                            const float* __restrict__ bias_table, const int* __restrict__ rel_index,
                            char* __restrict__ ws) {
    uint16_t* wq  = (uint16_t*)(ws + OFF_WQ);
    uint16_t* wp  = (uint16_t*)(ws + OFF_WP);
    float*    rb  = (float*)(ws + OFF_RB);
    float*    wsb = (float*)(ws + OFF_B);
    const int total = 196608 + 65536 + 32768 + 768;
    for (int idx = blockIdx.x * blockDim.x + threadIdx.x; idx < total;
         idx += gridDim.x * blockDim.x) {
        if (idx < 196608) {
            int n = idx >> 8, c = idx & 255;
            int src = (n < 512) ? ((n & ~31) | permd(n & 31)) : n;
            wq[idx] = (uint16_t)f2bf(qkv_w[src * 256 + c]);
        } else if (idx < 262144) {
            int i = idx - 196608;
            wp[i] = (uint16_t)f2bf(proj_w[i]);
        } else if (idx < 294912) {
            int i = idx - 262144;                 // [h][kt4][qt][ii]
            int h = i >> 12, kt4 = (i >> 8) & 15, qt = (i >> 2) & 63, ii = i & 3;
            int kt = kt4 * 4 + ii;
            float v = -1e30f;
            if (kt < 49 && qt < 49)
                v = bias_table[rel_index[qt * 49 + kt] * 8 + h] * 1.4426950408889634f;
            rb[i] = v;
        } else {
            int n = idx - 294912;
            int src = (n < 512) ? ((n & ~31) | permd(n & 31)) : n;
            wsb[n] = qkv_b[src];
        }
    }
}

// ---------------------------------------------------------------------------
// fused: 1 block = 1 window, 8 waves = 8 heads; LDS = X/O tile only.
// R6 skeleton + waves_per_eu(4,4) reg budget, wave-parity phase stagger,
// setprio on MFMA clusters, exp2-domain softmax, balanced proj.
// ---------------------------------------------------------------------------
__global__ __launch_bounds__(512)
__attribute__((amdgpu_waves_per_eu(4, 4)))
void fused_kernel(const float* __restrict__ x,
                  const float* __restrict__ proj_b,
                  float* __restrict__ out,
                  const char* __restrict__ ws) {
    __shared__ __align__(16) char smem[33792];   // X [64][264] bf16 ; later O [64][256] swz
    const int b = blockIdx.x;
    const int t = threadIdx.x, lane = t & 63, w = t >> 6;
    const int lr = lane & 15, lg = lane >> 4;
    const uint16_t* wq  = (const uint16_t*)(ws + OFF_WQ);
    const uint16_t* wp  = (const uint16_t*)(ws + OFF_WP);
    const float*    rb  = (const float*)(ws + OFF_RB);
    const float*    wsb = (const float*)(ws + OFF_B);
    uint16_t* X  = (uint16_t*)smem;
    char*     OL = smem;
    const float scale = 0.17677669529663687f * 1.4426950408889634f;  // /sqrt(32)/ln2

    // ---- stage x -> LDS bf16 [64][264], rows>=49 zero ----
    {
        const float4* xv = (const float4*)x;
        #pragma unroll
        for (int it = 0; it < 8; ++it) {
            int idx = it * 512 + t;
            int row = idx >> 6, c4 = idx & 63;
            uint32_t lo = 0, hi = 0;
            if (row < 49) {
                float4 v4 = xv[((int64_t)b * 49 + row) * 64 + c4];
                lo = pk2(v4.x, v4.y);
                hi = pk2(v4.z, v4.w);
            }
            uint32_t* p = (uint32_t*)(X + row * 264 + c4 * 4);
            p[0] = lo; p[1] = hi;
        }
    }
    __syncthreads();

    // ---- phase A: q,k transposed GEMMs (A=W rows, B=X frags) -> qf, kf ----
    bf16x8 qf[4], kf[4];
    {
        f32x4 aq[2][4], ak[2][4];
        #pragma unroll
        for (int mt = 0; mt < 2; ++mt)
            #pragma unroll
            for (int t4 = 0; t4 < 4; ++t4) {
                aq[mt][t4] = (f32x4){0.f, 0.f, 0.f, 0.f};
                ak[mt][t4] = (f32x4){0.f, 0.f, 0.f, 0.f};
            }
        #pragma unroll
        for (int kk = 0; kk < 8; ++kk) {
            bf16x8 xf[4];
            #pragma unroll
            for (int t4 = 0; t4 < 4; ++t4)
                xf[t4] = *(const bf16x8*)(X + (16 * t4 + lr) * 264 + kk * 32 + lg * 8);
            #pragma unroll
            for (int mt = 0; mt < 2; ++mt) {
                bf16x8 wfq = *(const bf16x8*)(wq + (w * 32 + 16 * mt + lr) * 256 + kk * 32 + lg * 8);
                bf16x8 wfk = *(const bf16x8*)(wq + (256 + w * 32 + 16 * mt + lr) * 256 + kk * 32 + lg * 8);
                #pragma unroll
                for (int t4 = 0; t4 < 4; ++t4) {
                    aq[mt][t4] = __builtin_amdgcn_mfma_f32_16x16x32_bf16(wfq, xf[t4], aq[mt][t4], 0, 0, 0);
                    ak[mt][t4] = __builtin_amdgcn_mfma_f32_16x16x32_bf16(wfk, xf[t4], ak[mt][t4], 0, 0, 0);
                }
            }
        }
        f32x4 bq[2], bk[2];
        #pragma unroll
        for (int mt = 0; mt < 2; ++mt) {
            bq[mt] = *(const f32x4*)(wsb + w * 32 + 16 * mt + 4 * lg);
            bk[mt] = *(const f32x4*)(wsb + 256 + w * 32 + 16 * mt + 4 * lg);
        }
        #pragma unroll
        for (int t4 = 0; t4 < 4; ++t4) {
            FragU q, k;
            #pragma unroll
            for (int mt = 0; mt < 2; ++mt) {
                q.u[2 * mt]     = pk2(aq[mt][t4][0] + bq[mt][0], aq[mt][t4][1] + bq[mt][1]);
                q.u[2 * mt + 1] = pk2(aq[mt][t4][2] + bq[mt][2], aq[mt][t4][3] + bq[mt][3]);
                k.u[2 * mt]     = pk2(ak[mt][t4][0] + bk[mt][0], ak[mt][t4][1] + bk[mt][1]);
                k.u[2 * mt + 1] = pk2(ak[mt][t4][2] + bk[mt][2], ak[mt][t4][3] + bk[mt][3]);
            }
            qf[t4] = q.v; kf[t4] = k.v;
        }
    }

    float rs[4];
    bf16x8 pf[4][2];
    bf16x8 vf[2][2];   // [dt][ks]

    // phase C/D: S col, softmax (exp2 domain), tau-pack pf
    auto phaseCD = [&]() {
        #pragma unroll
        for (int nj = 0; nj < 4; ++nj) {
            f32x4 s[4];
            __builtin_amdgcn_s_setprio(1);
            #pragma unroll
            for (int mj = 0; mj < 4; ++mj)
                s[mj] = __builtin_amdgcn_mfma_f32_16x16x32_bf16(
                    kf[mj], qf[nj], (f32x4){0.f, 0.f, 0.f, 0.f}, 0, 0, 0);
            __builtin_amdgcn_s_setprio(0);
            #pragma unroll
            for (int mj = 0; mj < 4; ++mj) {
                f32x4 rbv = *(const f32x4*)(rb + ((w * 16 + 4 * mj + lg) * 64 + 16 * nj + lr) * 4);
                s[mj] = s[mj] * scale + rbv;
            }
            float m = s[0][0];
            #pragma unroll
            for (int mj = 0; mj < 4; ++mj)
                #pragma unroll
                for (int i = 0; i < 4; ++i) m = fmaxf(m, s[mj][i]);
            m = fmaxf(m, __shfl_xor(m, 16));
            m = fmaxf(m, __shfl_xor(m, 32));
            float sum = 0.f;
            #pragma unroll
            for (int mj = 0; mj < 4; ++mj)
                #pragma unroll
                for (int i = 0; i < 4; ++i) {
                    float e = __builtin_amdgcn_exp2f(s[mj][i] - m);
                    s[mj][i] = e;
                    sum += e;
                }
            sum += __shfl_xor(sum, 16);
            sum += __shfl_xor(sum, 32);
            rs[nj] = sum;
            #pragma unroll
            for (int ks = 0; ks < 2; ++ks) {
                FragU f;
                f.u[0] = pk2(s[2 * ks][0], s[2 * ks][1]);
                f.u[1] = pk2(s[2 * ks][2], s[2 * ks][3]);
                f.u[2] = pk2(s[2 * ks + 1][0], s[2 * ks + 1][1]);
                f.u[3] = pk2(s[2 * ks + 1][2], s[2 * ks + 1][3]);
                pf[nj][ks] = f.v;
            }
        }
    };

    // phase B: v GEMM (A=X frags, B=Wv rows) + in-lane tau pack vf
    auto phaseB = [&]() {
        f32x4 av[4][2];
        #pragma unroll
        for (int t4 = 0; t4 < 4; ++t4)
            #pragma unroll
            for (int dn = 0; dn < 2; ++dn)
                av[t4][dn] = (f32x4){0.f, 0.f, 0.f, 0.f};
        #pragma unroll
        for (int kk = 0; kk < 8; ++kk) {
            bf16x8 xf[4];
            #pragma unroll
            for (int t4 = 0; t4 < 4; ++t4)
                xf[t4] = *(const bf16x8*)(X + (16 * t4 + lr) * 264 + kk * 32 + lg * 8);
            #pragma unroll
            for (int dn = 0; dn < 2; ++dn) {
                bf16x8 wf = *(const bf16x8*)(wq + (512 + w * 32 + 16 * dn + lr) * 256 + kk * 32 + lg * 8);
                #pragma unroll
                for (int t4 = 0; t4 < 4; ++t4)
                    av[t4][dn] = __builtin_amdgcn_mfma_f32_16x16x32_bf16(xf[t4], wf, av[t4][dn], 0, 0, 0);
            }
        }
        #pragma unroll
        for (int dt = 0; dt < 2; ++dt) {
            const float bv = wsb[512 + w * 32 + 16 * dt + lr];
            #pragma unroll
            for (int ks = 0; ks < 2; ++ks) {
                FragU f;
                f.u[0] = pk2(av[2 * ks][dt][0] + bv, av[2 * ks][dt][1] + bv);
                f.u[1] = pk2(av[2 * ks][dt][2] + bv, av[2 * ks][dt][3] + bv);
                f.u[2] = pk2(av[2 * ks + 1][dt][0] + bv, av[2 * ks + 1][dt][1] + bv);
                f.u[3] = pk2(av[2 * ks + 1][dt][2] + bv, av[2 * ks + 1][dt][3] + bv);
                vf[dt][ks] = f.v;
            }
        }
    };

    // wave-parity stagger: break the 8-wave lockstep so LDS/L2/MFMA bursts
    // from different waves interleave (and setprio has phases to arbitrate).
    if (w & 1) {
        phaseB();
        __builtin_amdgcn_sched_barrier(0);
        phaseCD();
    } else {
        phaseCD();
        __builtin_amdgcn_sched_barrier(0);
        phaseB();
    }

    // ---- phase E: O^T = V^T · P^T (tau-consistent k-slots) ----
    f32x4 o[2][4];
    __builtin_amdgcn_s_setprio(1);
    #pragma unroll
    for (int dt = 0; dt < 2; ++dt)
        #pragma unroll
        for (int nj = 0; nj < 4; ++nj) {
            f32x4 acc = __builtin_amdgcn_mfma_f32_16x16x32_bf16(
                vf[dt][0], pf[nj][0], (f32x4){0.f, 0.f, 0.f, 0.f}, 0, 0, 0);
            o[dt][nj] = __builtin_amdgcn_mfma_f32_16x16x32_bf16(vf[dt][1], pf[nj][1], acc, 0, 0, 0);
        }
    __builtin_amdgcn_s_setprio(0);

    // ---- phase F: normalize, O -> LDS (overlay X) ----
    __syncthreads();
    #pragma unroll
    for (int nj = 0; nj < 4; ++nj) {
        const float rinv = 1.0f / rs[nj];
        const int row = 16 * nj + lr;
        const int swz = (row & 7) << 4;
        #pragma unroll
        for (int dt = 0; dt < 2; ++dt) {
            uint2 pk;
            pk.x = pk2(o[dt][nj][0] * rinv, o[dt][nj][1] * rinv);
            pk.y = pk2(o[dt][nj][2] * rinv, o[dt][nj][3] * rinv);
            *(uint2*)(OL + ((row * 512 + w * 64 + dt * 32 + lg * 8) ^ swz)) = pk;
        }
    }
    __syncthreads();

    // ---- phase G: proj GEMM, wave w -> cols [w*32, w*32+32), all 64 rows ----
    f32x4 pacc[4][2];
    #pragma unroll
    for (int mi = 0; mi < 4; ++mi)
        #pragma unroll
        for (int nj = 0; nj < 2; ++nj)
            pacc[mi][nj] = (f32x4){0.f, 0.f, 0.f, 0.f};
    #pragma unroll
    for (int kk = 0; kk < 8; ++kk) {
        bf16x8 av[4];
        #pragma unroll
        for (int mi = 0; mi < 4; ++mi) {
            const int row = mi * 16 + lr;
            av[mi] = *(const bf16x8*)(OL + ((row * 512 + kk * 64 + lg * 16) ^ ((row & 7) << 4)));
        }
        #pragma unroll
        for (int nj = 0; nj < 2; ++nj) {
            bf16x8 bv = *(const bf16x8*)(wp + (w * 32 + nj * 16 + lr) * 256 + kk * 32 + lg * 8);
            #pragma unroll
            for (int mi = 0; mi < 4; ++mi)
                pacc[mi][nj] = __builtin_amdgcn_mfma_f32_16x16x32_bf16(av[mi], bv, pacc[mi][nj], 0, 0, 0);
        }
    }
    #pragma unroll
    for (int nj = 0; nj < 2; ++nj) {
        const int n = w * 32 + nj * 16 + lr;
        const float pb = proj_b[n];
        #pragma unroll
        for (int mi = 0; mi < 4; ++mi)
            #pragma unroll
            for (int i = 0; i < 4; ++i) {
                const int tok = mi * 16 + lg * 4 + i;
                if (tok < 49)
                    out[((int64_t)b * 49 + tok) * 256 + n] = pacc[mi][nj][i] + pb;
            }
    }
}

extern "C" void kernel_launch(void* const* d_in, const int* in_sizes, int n_in,
                              void* d_out, int out_size, void* d_ws, size_t ws_size,
                              hipStream_t stream) {
    const float* x          = (const float*)d_in[0];
    const float* qkv_w      = (const float*)d_in[1];
    const float* qkv_b      = (const float*)d_in[2];
    const float* proj_w     = (const float*)d_in[3];
    const float* proj_b     = (const float*)d_in[4];
    const float* bias_table = (const float*)d_in[5];
    const int*   rel_index  = (const int*)d_in[6];
    float* out = (float*)d_out;
    char*  ws  = (char*)d_ws;

    prep_kernel<<<1155, 256, 0, stream>>>(qkv_w, proj_w, qkv_b, bias_table, rel_index, ws);
    fused_kernel<<<NWIN, 512, 0, stream>>>(x, proj_b, out, ws);
}

// Round 8
// 369.748 us; speedup vs baseline: 2.1190x; 1.0665x over previous
//
#include <hip/hip_runtime.h>
#include <hip/hip_bf16.h>
#include <stdint.h>

#define NWIN 4096

typedef __attribute__((ext_vector_type(8))) short bf16x8;
typedef __attribute__((ext_vector_type(4))) float f32x4;

// ws layout (bytes):
//   wq' bf16 [768][256] @0        (q/k rows permuted by pi within each 32-row head slice)
//   wp  bf16 [256][256] @393216
//   rb2 f32  [8][16][64][4] @524288   ([h][kt>>2][qt][kt&3], *1/ln2, kt>=49 -> -1e30)
//   wsb f32  [768] @655360            (qkv bias, q/k permuted to match wq')
#define OFF_WQ 0LL
#define OFF_WP 393216LL
#define OFF_RB 524288LL
#define OFF_B  655360LL

static __device__ __forceinline__ uint32_t f2bf(float f) {
    union { float f; uint32_t u; } v; v.f = f;
    return (v.u + 0x7FFFu + ((v.u >> 16) & 1u)) >> 16;
}

static __device__ __forceinline__ uint32_t pk2(float lo, float hi) {
    union { __hip_bfloat162 h; uint32_t u; } c;
    c.h = __float22bfloat162_rn(float2{lo, hi});
    return c.u;
}

// pi: acc position p=16mt+4lg+i  ->  d = 8lg+4mt+i
static __device__ __forceinline__ int permd(int p) {
    return ((p >> 2) & 3) * 8 + (p >> 4) * 4 + (p & 3);
}

union FragU { uint32_t u[4]; bf16x8 v; };

// ---------------------------------------------------------------------------
// prep
// ---------------------------------------------------------------------------
__global__ void prep_kernel(const float* __restrict__ qkv_w, const float* __restrict__ proj_w,
                            const float* __restrict__ qkv_b,
                            const float* __restrict__ bias_table, const int* __restrict__ rel_index,
                            char* __restrict__ ws) {
    uint16_t* wq  = (uint16_t*)(ws + OFF_WQ);
    uint16_t* wp  = (uint16_t*)(ws + OFF_WP);
    float*    rb  = (float*)(ws + OFF_RB);
    float*    wsb = (float*)(ws + OFF_B);
    const int total = 196608 + 65536 + 32768 + 768;
    for (int idx = blockIdx.x * blockDim.x + threadIdx.x; idx < total;
         idx += gridDim.x * blockDim.x) {
        if (idx < 196608) {
            int n = idx >> 8, c = idx & 255;
            int src = (n < 512) ? ((n & ~31) | permd(n & 31)) : n;
            wq[idx] = (uint16_t)f2bf(qkv_w[src * 256 + c]);
        } else if (idx < 262144) {
            int i = idx - 196608;
            wp[i] = (uint16_t)f2bf(proj_w[i]);
        } else if (idx < 294912) {
            int i = idx - 262144;                 // [h][kt4][qt][ii]
            int h = i >> 12, kt4 = (i >> 8) & 15, qt = (i >> 2) & 63, ii = i & 3;
            int kt = kt4 * 4 + ii;
            float v = -1e30f;
            if (kt < 49 && qt < 49)
                v = bias_table[rel_index[qt * 49 + kt] * 8 + h] * 1.4426950408889634f;
            rb[i] = v;
        } else {
            int n = idx - 294912;
            int src = (n < 512) ? ((n & ~31) | permd(n & 31)) : n;
            wsb[n] = qkv_b[src];
        }
    }
}

// ---------------------------------------------------------------------------
// fused: 1 block = 1 window, 8 waves = 8 heads; LDS = X/O tile only.
// R6 schedule (no-spill proven) + 128-VGPR budget via launch_bounds(512,2)
// (r2-proven), exp2-domain softmax, balanced proj-G, setprio on MFMA clusters.
// ---------------------------------------------------------------------------
__global__ __launch_bounds__(512, 2) void fused_kernel(const float* __restrict__ x,
                                                       const float* __restrict__ proj_b,
                                                       float* __restrict__ out,
                                                       const char* __restrict__ ws) {
    __shared__ __align__(16) char smem[33792];   // X [64][264] bf16 ; later O [64][256] swz
    const int b = blockIdx.x;
    const int t = threadIdx.x, lane = t & 63, w = t >> 6;
    const int lr = lane & 15, lg = lane >> 4;
    const uint16_t* wq  = (const uint16_t*)(ws + OFF_WQ);
    const uint16_t* wp  = (const uint16_t*)(ws + OFF_WP);
    const float*    rb  = (const float*)(ws + OFF_RB);
    const float*    wsb = (const float*)(ws + OFF_B);
    uint16_t* X  = (uint16_t*)smem;
    char*     OL = smem;
    const float scale = 0.17677669529663687f * 1.4426950408889634f;  // /sqrt(32)/ln2

    // ---- stage x -> LDS bf16 [64][264], rows>=49 zero ----
    {
        const float4* xv = (const float4*)x;
        #pragma unroll
        for (int it = 0; it < 8; ++it) {
            int idx = it * 512 + t;
            int row = idx >> 6, c4 = idx & 63;
            uint32_t lo = 0, hi = 0;
            if (row < 49) {
                float4 v4 = xv[((int64_t)b * 49 + row) * 64 + c4];
                lo = pk2(v4.x, v4.y);
                hi = pk2(v4.z, v4.w);
            }
            uint32_t* p = (uint32_t*)(X + row * 264 + c4 * 4);
            p[0] = lo; p[1] = hi;
        }
    }
    __syncthreads();

    // ---- phase A: q,k transposed GEMMs (A=W rows, B=X frags) -> qf, kf ----
    bf16x8 qf[4], kf[4];
    {
        f32x4 aq[2][4], ak[2][4];
        #pragma unroll
        for (int mt = 0; mt < 2; ++mt)
            #pragma unroll
            for (int t4 = 0; t4 < 4; ++t4) {
                aq[mt][t4] = (f32x4){0.f, 0.f, 0.f, 0.f};
                ak[mt][t4] = (f32x4){0.f, 0.f, 0.f, 0.f};
            }
        #pragma unroll
        for (int kk = 0; kk < 8; ++kk) {
            bf16x8 xf[4];
            #pragma unroll
            for (int t4 = 0; t4 < 4; ++t4)
                xf[t4] = *(const bf16x8*)(X + (16 * t4 + lr) * 264 + kk * 32 + lg * 8);
            #pragma unroll
            for (int mt = 0; mt < 2; ++mt) {
                bf16x8 wfq = *(const bf16x8*)(wq + (w * 32 + 16 * mt + lr) * 256 + kk * 32 + lg * 8);
                bf16x8 wfk = *(const bf16x8*)(wq + (256 + w * 32 + 16 * mt + lr) * 256 + kk * 32 + lg * 8);
                #pragma unroll
                for (int t4 = 0; t4 < 4; ++t4) {
                    aq[mt][t4] = __builtin_amdgcn_mfma_f32_16x16x32_bf16(wfq, xf[t4], aq[mt][t4], 0, 0, 0);
                    ak[mt][t4] = __builtin_amdgcn_mfma_f32_16x16x32_bf16(wfk, xf[t4], ak[mt][t4], 0, 0, 0);
                }
            }
        }
        f32x4 bq[2], bk[2];
        #pragma unroll
        for (int mt = 0; mt < 2; ++mt) {
            bq[mt] = *(const f32x4*)(wsb + w * 32 + 16 * mt + 4 * lg);
            bk[mt] = *(const f32x4*)(wsb + 256 + w * 32 + 16 * mt + 4 * lg);
        }
        #pragma unroll
        for (int t4 = 0; t4 < 4; ++t4) {
            FragU q, k;
            #pragma unroll
            for (int mt = 0; mt < 2; ++mt) {
                q.u[2 * mt]     = pk2(aq[mt][t4][0] + bq[mt][0], aq[mt][t4][1] + bq[mt][1]);
                q.u[2 * mt + 1] = pk2(aq[mt][t4][2] + bq[mt][2], aq[mt][t4][3] + bq[mt][3]);
                k.u[2 * mt]     = pk2(ak[mt][t4][0] + bk[mt][0], ak[mt][t4][1] + bk[mt][1]);
                k.u[2 * mt + 1] = pk2(ak[mt][t4][2] + bk[mt][2], ak[mt][t4][3] + bk[mt][3]);
            }
            qf[t4] = q.v; kf[t4] = k.v;
        }
    }

    // ---- phase C/D streamed per qt-group: S col, softmax (exp2), tau-pack pf ----
    float rs[4];
    bf16x8 pf[4][2];
    #pragma unroll
    for (int nj = 0; nj < 4; ++nj) {
        f32x4 s[4];
        __builtin_amdgcn_s_setprio(1);
        #pragma unroll
        for (int mj = 0; mj < 4; ++mj)
            s[mj] = __builtin_amdgcn_mfma_f32_16x16x32_bf16(
                kf[mj], qf[nj], (f32x4){0.f, 0.f, 0.f, 0.f}, 0, 0, 0);
        __builtin_amdgcn_s_setprio(0);
        #pragma unroll
        for (int mj = 0; mj < 4; ++mj) {
            f32x4 rbv = *(const f32x4*)(rb + ((w * 16 + 4 * mj + lg) * 64 + 16 * nj + lr) * 4);
            s[mj] = s[mj] * scale + rbv;
        }
        float m = s[0][0];
        #pragma unroll
        for (int mj = 0; mj < 4; ++mj)
            #pragma unroll
            for (int i = 0; i < 4; ++i) m = fmaxf(m, s[mj][i]);
        m = fmaxf(m, __shfl_xor(m, 16));
        m = fmaxf(m, __shfl_xor(m, 32));
        float sum = 0.f;
        #pragma unroll
        for (int mj = 0; mj < 4; ++mj)
            #pragma unroll
            for (int i = 0; i < 4; ++i) {
                float e = __builtin_amdgcn_exp2f(s[mj][i] - m);
                s[mj][i] = e;
                sum += e;
            }
        sum += __shfl_xor(sum, 16);
        sum += __shfl_xor(sum, 32);
        rs[nj] = sum;
        // in-lane tau pack: fragment ks = pack(s[2ks], s[2ks+1])
        #pragma unroll
        for (int ks = 0; ks < 2; ++ks) {
            FragU f;
            f.u[0] = pk2(s[2 * ks][0], s[2 * ks][1]);
            f.u[1] = pk2(s[2 * ks][2], s[2 * ks][3]);
            f.u[2] = pk2(s[2 * ks + 1][0], s[2 * ks + 1][1]);
            f.u[3] = pk2(s[2 * ks + 1][2], s[2 * ks + 1][3]);
            pf[nj][ks] = f.v;
        }
    }

    // keep v-GEMM loads/MFMAs from being hoisted into the softmax region
    __builtin_amdgcn_sched_barrier(0);

    // ---- phase B: v GEMM (A=X frags, B=Wv rows) + in-lane tau pack vf ----
    bf16x8 vf[2][2];   // [dt][ks]
    {
        f32x4 av[4][2];
        #pragma unroll
        for (int t4 = 0; t4 < 4; ++t4)
            #pragma unroll
            for (int dn = 0; dn < 2; ++dn)
                av[t4][dn] = (f32x4){0.f, 0.f, 0.f, 0.f};
        #pragma unroll
        for (int kk = 0; kk < 8; ++kk) {
            bf16x8 xf[4];
            #pragma unroll
            for (int t4 = 0; t4 < 4; ++t4)
                xf[t4] = *(const bf16x8*)(X + (16 * t4 + lr) * 264 + kk * 32 + lg * 8);
            #pragma unroll
            for (int dn = 0; dn < 2; ++dn) {
                bf16x8 wf = *(const bf16x8*)(wq + (512 + w * 32 + 16 * dn + lr) * 256 + kk * 32 + lg * 8);
                #pragma unroll
                for (int t4 = 0; t4 < 4; ++t4)
                    av[t4][dn] = __builtin_amdgcn_mfma_f32_16x16x32_bf16(xf[t4], wf, av[t4][dn], 0, 0, 0);
            }
        }
        #pragma unroll
        for (int dt = 0; dt < 2; ++dt) {
            const float bv = wsb[512 + w * 32 + 16 * dt + lr];
            #pragma unroll
            for (int ks = 0; ks < 2; ++ks) {
                FragU f;
                f.u[0] = pk2(av[2 * ks][dt][0] + bv, av[2 * ks][dt][1] + bv);
                f.u[1] = pk2(av[2 * ks][dt][2] + bv, av[2 * ks][dt][3] + bv);
                f.u[2] = pk2(av[2 * ks + 1][dt][0] + bv, av[2 * ks + 1][dt][1] + bv);
                f.u[3] = pk2(av[2 * ks + 1][dt][2] + bv, av[2 * ks + 1][dt][3] + bv);
                vf[dt][ks] = f.v;
            }
        }
    }

    // ---- phase E: O^T = V^T · P^T (tau-consistent k-slots) ----
    f32x4 o[2][4];
    __builtin_amdgcn_s_setprio(1);
    #pragma unroll
    for (int dt = 0; dt < 2; ++dt)
        #pragma unroll
        for (int nj = 0; nj < 4; ++nj) {
            f32x4 acc = __builtin_amdgcn_mfma_f32_16x16x32_bf16(
                vf[dt][0], pf[nj][0], (f32x4){0.f, 0.f, 0.f, 0.f}, 0, 0, 0);
            o[dt][nj] = __builtin_amdgcn_mfma_f32_16x16x32_bf16(vf[dt][1], pf[nj][1], acc, 0, 0, 0);
        }
    __builtin_amdgcn_s_setprio(0);

    // ---- phase F: normalize, O -> LDS (overlay X) ----
    __syncthreads();
    #pragma unroll
    for (int nj = 0; nj < 4; ++nj) {
        const float rinv = 1.0f / rs[nj];
        const int row = 16 * nj + lr;
        const int swz = (row & 7) << 4;
        #pragma unroll
        for (int dt = 0; dt < 2; ++dt) {
            uint2 pk;
            pk.x = pk2(o[dt][nj][0] * rinv, o[dt][nj][1] * rinv);
            pk.y = pk2(o[dt][nj][2] * rinv, o[dt][nj][3] * rinv);
            *(uint2*)(OL + ((row * 512 + w * 64 + dt * 32 + lg * 8) ^ swz)) = pk;
        }
    }
    __syncthreads();

    // ---- phase G: proj GEMM, wave w -> cols [w*32, w*32+32), all 64 rows ----
    f32x4 pacc[4][2];
    #pragma unroll
    for (int mi = 0; mi < 4; ++mi)
        #pragma unroll
        for (int nj = 0; nj < 2; ++nj)
            pacc[mi][nj] = (f32x4){0.f, 0.f, 0.f, 0.f};
    #pragma unroll
    for (int kk = 0; kk < 8; ++kk) {
        bf16x8 av[4];
        #pragma unroll
        for (int mi = 0; mi < 4; ++mi) {
            const int row = mi * 16 + lr;
            av[mi] = *(const bf16x8*)(OL + ((row * 512 + kk * 64 + lg * 16) ^ ((row & 7) << 4)));
        }
        #pragma unroll
        for (int nj = 0; nj < 2; ++nj) {
            bf16x8 bv = *(const bf16x8*)(wp + (w * 32 + nj * 16 + lr) * 256 + kk * 32 + lg * 8);
            #pragma unroll
            for (int mi = 0; mi < 4; ++mi)
                pacc[mi][nj] = __builtin_amdgcn_mfma_f32_16x16x32_bf16(av[mi], bv, pacc[mi][nj], 0, 0, 0);
        }
    }
    #pragma unroll
    for (int nj = 0; nj < 2; ++nj) {
        const int n = w * 32 + nj * 16 + lr;
        const float pb = proj_b[n];
        #pragma unroll
        for (int mi = 0; mi < 4; ++mi)
            #pragma unroll
            for (int i = 0; i < 4; ++i) {
                const int tok = mi * 16 + lg * 4 + i;
                if (tok < 49)
                    out[((int64_t)b * 49 + tok) * 256 + n] = pacc[mi][nj][i] + pb;
            }
    }
}

extern "C" void kernel_launch(void* const* d_in, const int* in_sizes, int n_in,
                              void* d_out, int out_size, void* d_ws, size_t ws_size,
                              hipStream_t stream) {
    const float* x          = (const float*)d_in[0];
    const float* qkv_w      = (const float*)d_in[1];
    const float* qkv_b      = (const float*)d_in[2];
    const float* proj_w     = (const float*)d_in[3];
    const float* proj_b     = (const float*)d_in[4];
    const float* bias_table = (const float*)d_in[5];
    const int*   rel_index  = (const int*)d_in[6];
    float* out = (float*)d_out;
    char*  ws  = (char*)d_ws;

    prep_kernel<<<1155, 256, 0, stream>>>(qkv_w, proj_w, qkv_b, bias_table, rel_index, ws);
    fused_kernel<<<NWIN, 512, 0, stream>>>(x, proj_b, out, ws);
}